// Round 15
// baseline (32.079 us; speedup 1.0000x reference)
//
#include <hip/hip_runtime.h>

// LePE window attention, 32x32x16 bf16 MFMA, reg-P via v_permlane32_swap_b32.
// R15: cross-block phase-overlap probe. Grid 512 = (window, head, q-half),
// 512 threads (8 waves x 32 q rows); 2 blocks/CU co-resident (147 KB LDS,
// 16 waves/CU -> 128-VGPR cap, no spill) so one block's staging memory phase
// overlaps the other's compute phase. Staging duplicated per q-half (+16 MB
// FETCH, accepted). vu now double-buffered like kf (LDS latency hides under
// the exp chain). Body otherwise = R14 (no setprio, ones-MFMA lsum).
// LDS = K[512][40] + V^T[32][536] bf16 = 73.5 KB per block.

namespace {
constexpr int Bn   = 8;
constexpr int Ww   = 64;
constexpr int Cc   = 128;
constexpr int HD   = 32;
constexpr int WSP  = 8;
constexpr int NTOK = 512;
constexpr int LL   = 64 * 64;
// 32^-0.5 * log2(e): exp(s) == exp2(s') with scale folded into Q
constexpr float SCALE_L2E = 0.17677669529663687f * 1.4426950408889634f;
constexpr int KPAD = 40;   // K row stride in shorts (80B rows -> 16B-aligned frags)
constexpr int VPAD = 536;  // V^T row stride in shorts (1072B rows -> 16B-aligned)
}

typedef __bf16 bf16x8 __attribute__((ext_vector_type(8)));
typedef float  f32x16 __attribute__((ext_vector_type(16)));
typedef unsigned int uint32x4 __attribute__((ext_vector_type(4)));

// dst.lo = bf16(x), dst.hi = bf16(y) — single VALU op (RNE)
__device__ inline unsigned cvtpk(float x, float y) {
    unsigned r;
    asm("v_cvt_pk_bf16_f32 %0, %1, %2" : "=v"(r) : "v"(x), "v"(y));
    return r;
}

__global__ __launch_bounds__(512, 4) void attn_kernel(const float* __restrict__ qkv,
                                                      const float* __restrict__ cw,
                                                      const float* __restrict__ cb,
                                                      float* __restrict__ out) {
    const int blk = blockIdx.x;          // 0..511
    const int w   = blk >> 3;            // window 0..63
    const int h   = (blk >> 1) & 3;      // head
    const int qh  = blk & 1;             // q half (256 rows)
    const int b   = w >> 3;
    const int wb  = w & 7;
    const int tid = threadIdx.x;         // 0..511
    const int wv  = tid >> 6;            // wave 0..7 -> 32 q rows each
    const int lane = tid & 63;
    const int l31 = lane & 31;
    const int h5  = lane >> 5;

    const float* qp = qkv;
    const float* kp = qkv + (size_t)Bn * LL * Cc;
    const float* vp = qkv + (size_t)2 * Bn * LL * Cc;

    __shared__ short K_lds[NTOK][KPAD];
    __shared__ short VT_lds[HD][VPAD];

    // ---- Q fragments: q tok = qh*256 + wv*32 + l31, d = dc*16 + h5*8 + e ----
    const int qtok = qh * 256 + wv * 32 + l31;
    const int qlqi = (qtok >> 3) * Ww + wb * WSP + (qtok & 7);
    bf16x8 qf[2];
    {
        const float* p = qp + ((size_t)b * LL + qlqi) * Cc + h * HD + h5 * 8;
#pragma unroll
        for (int dc = 0; dc < 2; ++dc) {
            float4 a = *reinterpret_cast<const float4*>(p + dc * 16);
            float4 c = *reinterpret_cast<const float4*>(p + dc * 16 + 4);
            uint32x4 u;
            u.x = cvtpk(a.x * SCALE_L2E, a.y * SCALE_L2E);
            u.y = cvtpk(a.z * SCALE_L2E, a.w * SCALE_L2E);
            u.z = cvtpk(c.x * SCALE_L2E, c.y * SCALE_L2E);
            u.w = cvtpk(c.z * SCALE_L2E, c.w * SCALE_L2E);
            qf[dc] = __builtin_bit_cast(bf16x8, u);
        }
    }

    // ---- stage K and V^T (bf16), token-pair scheme: 2048 items / 512 thr ----
    for (int i = tid; i < (NTOK / 2) * 8; i += 512) {
        const int tp = i >> 3, j = i & 7;      // token pair, d-group
        const int t0 = tp * 2, t1 = t0 + 1;
        const int lqi0 = (t0 >> 3) * Ww + wb * WSP + (t0 & 7);  // lqi1 = lqi0+1
        const size_t b0 = ((size_t)b * LL + lqi0) * Cc + h * HD + j * 4;
        const float4 k0 = *reinterpret_cast<const float4*>(kp + b0);
        const float4 k1 = *reinterpret_cast<const float4*>(kp + b0 + Cc);
        uint2 pk0, pk1;
        pk0.x = cvtpk(k0.x, k0.y);  pk0.y = cvtpk(k0.z, k0.w);
        pk1.x = cvtpk(k1.x, k1.y);  pk1.y = cvtpk(k1.z, k1.w);
        *reinterpret_cast<uint2*>(&K_lds[t0][j * 4]) = pk0;
        *reinterpret_cast<uint2*>(&K_lds[t1][j * 4]) = pk1;
        const float4 v0 = *reinterpret_cast<const float4*>(vp + b0);
        const float4 v1 = *reinterpret_cast<const float4*>(vp + b0 + Cc);
        *reinterpret_cast<unsigned*>(&VT_lds[j * 4 + 0][t0]) = cvtpk(v0.x, v1.x);
        *reinterpret_cast<unsigned*>(&VT_lds[j * 4 + 1][t0]) = cvtpk(v0.y, v1.y);
        *reinterpret_cast<unsigned*>(&VT_lds[j * 4 + 2][t0]) = cvtpk(v0.z, v1.z);
        *reinterpret_cast<unsigned*>(&VT_lds[j * 4 + 3][t0]) = cvtpk(v0.w, v1.w);
    }
    __syncthreads();   // the only barrier

    f32x16 acc  = (f32x16)(0.f);
    f32x16 lacc = (f32x16)(0.f);         // row-sum accumulator (ones-MFMA)
    const f32x16 z16 = (f32x16)(0.f);

    // ones B-fragment: every element bf16 1.0
    uint32x4 onesu;
    onesu.x = 0x3F803F80u; onesu.y = 0x3F803F80u;
    onesu.z = 0x3F803F80u; onesu.w = 0x3F803F80u;
    const bf16x8 onesf = __builtin_bit_cast(bf16x8, onesu);

    auto load_kf = [&](int kt, bf16x8* kf) {
        const int krow = kt * 32 + l31;
#pragma unroll
        for (int dc = 0; dc < 2; ++dc)
            kf[dc] = __builtin_bit_cast(bf16x8,
                *reinterpret_cast<const uint32x4*>(&K_lds[krow][dc * 16 + h5 * 8]));
    };
    auto load_vu = [&](int kt, uint32x4* vu) {
#pragma unroll
        for (int kw = 0; kw < 2; ++kw) {
            const int kcol = kt * 32 + kw * 16 + h5 * 8;
            vu[kw] = *reinterpret_cast<const uint32x4*>(&VT_lds[l31][kcol]);
        }
    };

    bf16x8 kf[2];
    uint32x4 vu[2];
    load_kf(0, kf);
    load_vu(0, vu);

    // ---- main loop: 16 tiles of 32 keys, barrier-free ----
    for (int kt = 0; kt < 16; ++kt) {
        f32x16 s = z16;
        s = __builtin_amdgcn_mfma_f32_32x32x16_bf16(kf[0], qf[0], s, 0, 0, 0);
        s = __builtin_amdgcn_mfma_f32_32x32x16_bf16(kf[1], qf[1], s, 0, 0, 0);
        // lane holds S^T[k][q=l31], k = (reg&3) + 8*(reg>>2) + 4*h5 + kt*32

        // prefetch next tile's K and V fragments; latency hides under exp chain
        bf16x8 kfn[2];
        uint32x4 vun[2];
        load_kf((kt + 1) & 15, kfn);
        load_vu((kt + 1) & 15, vun);

        float pe[16];
#pragma unroll
        for (int i = 0; i < 16; ++i) pe[i] = __builtin_amdgcn_exp2f(s[i]);
        unsigned dw[8];
#pragma unroll
        for (int i = 0; i < 8; ++i) dw[i] = cvtpk(pe[2 * i], pe[2 * i + 1]);

        // PV + row-sum: per 16-key window kw, redistribute P across the h5
        // halves with 2x v_permlane32_swap_b32 (vdst_hi <-> vsrc_lo), then
        // one PV MFMA and one ones-MFMA (row sums, same r<->q map as acc).
#pragma unroll
        for (int kw = 0; kw < 2; ++kw) {
            unsigned a0 = dw[4 * kw + 0], b0 = dw[4 * kw + 2];
            unsigned a1 = dw[4 * kw + 1], b1 = dw[4 * kw + 3];
            asm("v_permlane32_swap_b32 %0, %1" : "+v"(a0), "+v"(b0));
            asm("v_permlane32_swap_b32 %0, %1" : "+v"(a1), "+v"(b1));
            uint32x4 pu; pu.x = a0; pu.y = a1; pu.z = b0; pu.w = b1;
            const bf16x8 pf = __builtin_bit_cast(bf16x8, pu);
            acc  = __builtin_amdgcn_mfma_f32_32x32x16_bf16(
                pf, __builtin_bit_cast(bf16x8, vu[kw]), acc, 0, 0, 0);
            lacc = __builtin_amdgcn_mfma_f32_32x32x16_bf16(
                pf, onesf, lacc, 0, 0, 0);
        }
        kf[0] = kfn[0];
        kf[1] = kfn[1];
        vu[0] = vun[0];
        vu[1] = vun[1];
    }

    // ---- LePE conv: lane owns channel d = l31 of head h ----
    const int ch = h * HD + l31;
    float wreg[9];
#pragma unroll
    for (int wi = 0; wi < 9; ++wi) wreg[wi] = cw[ch * 9 + wi];
    const float bias = cb[ch];

    const int tok0 = qh * 256 + wv * 32;
    // Packed V halo: 52 bf16 toks [tok0 + 4*h5 - 12, +40) as 26 uints.
    // Needed tap range rel. tok0+4h5 is [-9,+36]; clamped chunk slots are only
    // tokens <0 / >=512, all rowok-guarded below.
    unsigned hw[26];
    {
        const int segbase = tok0 + 4 * h5 - 12;
#pragma unroll
        for (int c2 = 0; c2 < 13; ++c2) {
            int t = segbase + 4 * c2;
            t = t < 0 ? 0 : (t > NTOK - 4 ? NTOK - 4 : t);
            const uint2 u = *reinterpret_cast<const uint2*>(&VT_lds[l31][t]);
            hw[c2 * 2 + 0] = u.x;
            hw[c2 * 2 + 1] = u.y;
        }
    }

    // ---- epilogue: normalize (in-lane rcp of lacc) + conv + store ----
#pragma unroll
    for (int r = 0; r < 16; ++r) {
        const int c_r = (r & 3) + 8 * (r >> 2);           // q row offset (compile-time)
        const float iv = __builtin_amdgcn_rcpf(lacc[r]);  // 1/lsum for q_r, in-lane
        const int tok = tok0 + c_r + 4 * h5;
        float cv = bias;
#pragma unroll
        for (int dy = -1; dy <= 1; ++dy) {
            const bool rowok = (unsigned)(tok + dy * 8) < (unsigned)NTOK;
#pragma unroll
            for (int dx = -1; dx <= 1; ++dx) {
                const int idx = c_r + 12 + dy * 8 + dx;   // compile-time, in [3,48]
                const unsigned word = hw[idx >> 1];
                const float tap = __builtin_bit_cast(float,
                    (idx & 1) ? (word & 0xFFFF0000u) : (word << 16));
                bool ok = rowok;
                if (dx == -1) ok = ok && (((r & 3) != 0) || (h5 != 0));  // wc > 0
                if (dx == +1) ok = ok && (((r & 3) != 3) || (h5 == 0));  // wc < 7
                cv += ok ? wreg[(dy + 1) * 3 + (dx + 1)] * tap : 0.f;
            }
        }
        const int lqi = (tok >> 3) * Ww + wb * WSP + (tok & 7);
        out[((size_t)b * LL + lqi) * Cc + ch] = acc[r] * iv + cv;
    }
}

extern "C" void kernel_launch(void* const* d_in, const int* in_sizes, int n_in,
                              void* d_out, int out_size, void* d_ws, size_t ws_size,
                              hipStream_t stream) {
    const float* qkv = (const float*)d_in[0];
    const float* cw  = (const float*)d_in[1];
    const float* cb  = (const float*)d_in[2];
    float* out = (float*)d_out;

    attn_kernel<<<512, 512, 0, stream>>>(qkv, cw, cb, out);
}